// Round 15
// baseline (106.020 us; speedup 1.0000x reference)
//
#include <hip/hip_runtime.h>

#define T_LEN 32768
#define DIM   300
#define NCH   75     // DIM/4 float4 chunks per row
#define NP    5      // superdiagonal entries
#define TB    16     // window starts per block
#define ROWS  20     // TB + NP - 1 t's per block (4 halo)
#define NBLK  (T_LEN / TB)   // 2048

__device__ __forceinline__ float fast_sigmoid(float z) {
    return 1.0f / (1.0f + __expf(-z));
}

// 320 threads = 5 waves = 20 groups of 16 lanes; group g owns t = t0 + g.
// All 20 gathers issue in parallel at kernel start (no phase serialization,
// the structure rounds 3/9/10 validated). One barrier, then wave 0 forms the
// 16 window products and plain-stores ONE partial per block -> no atomics
// (2048 same-address atomicAdds cost ~30-50us in rounds 1/8).
__global__ __launch_bounds__(320, 8) void fused_block(
    const int*   __restrict__ doc,      // [T]
    const float* __restrict__ emb,      // [VOCAB, 300]
    const float* __restrict__ w,        // [6, 6, 300]
    const float* __restrict__ b,        // [6, 6]
    float*       __restrict__ partial)  // ws: [NBLK]
{
    __shared__ float lds_v[ROWS][NP];

    const int tid = threadIdx.x;
    const int g   = tid >> 4;       // 0..19
    const int sub = tid & 15;
    const int t0  = blockIdx.x * TB;
    const int t   = t0 + g;
    // Halo t's of the last block run past T_LEN: clamp the index (their vals
    // are computed but provably never used by any guarded window product).
    const int tc  = (t < T_LEN) ? t : (T_LEN - 1);

    // ---- Issue the 5 long-latency gather loads first ----
    const float* __restrict__ xrow = emb + (size_t)doc[tc] * DIM;
    const float4 x0 = *reinterpret_cast<const float4*>(xrow + 4 * (sub));
    const float4 x1 = *reinterpret_cast<const float4*>(xrow + 4 * (sub + 16));
    const float4 x2 = *reinterpret_cast<const float4*>(xrow + 4 * (sub + 32));
    const float4 x3 = *reinterpret_cast<const float4*>(xrow + 4 * (sub + 48));
    float4 x4 = make_float4(0.f, 0.f, 0.f, 0.f);
    if (sub < NCH - 64)
        x4 = *reinterpret_cast<const float4*>(xrow + 4 * (sub + 64));

    float a0 = 0.f, a1 = 0.f, a2 = 0.f, a3 = 0.f, a4 = 0.f;

    // w superdiagonal row i at flat row 7i+1; identical across blocks -> L1/L2 hits.
    #define ACC(xv, c)                                                                  \
        {                                                                               \
            const float4 w0 = *reinterpret_cast<const float4*>(w + 1  * DIM + 4 * (c)); \
            const float4 w1 = *reinterpret_cast<const float4*>(w + 8  * DIM + 4 * (c)); \
            const float4 w2 = *reinterpret_cast<const float4*>(w + 15 * DIM + 4 * (c)); \
            const float4 w3 = *reinterpret_cast<const float4*>(w + 22 * DIM + 4 * (c)); \
            const float4 w4 = *reinterpret_cast<const float4*>(w + 29 * DIM + 4 * (c)); \
            a0 += (xv).x * w0.x + (xv).y * w0.y + (xv).z * w0.z + (xv).w * w0.w;        \
            a1 += (xv).x * w1.x + (xv).y * w1.y + (xv).z * w1.z + (xv).w * w1.w;        \
            a2 += (xv).x * w2.x + (xv).y * w2.y + (xv).z * w2.z + (xv).w * w2.w;        \
            a3 += (xv).x * w3.x + (xv).y * w3.y + (xv).z * w3.z + (xv).w * w3.w;        \
            a4 += (xv).x * w4.x + (xv).y * w4.y + (xv).z * w4.z + (xv).w * w4.w;        \
        }
    ACC(x0, sub);
    ACC(x1, sub + 16);
    ACC(x2, sub + 32);
    ACC(x3, sub + 48);
    if (sub < NCH - 64) ACC(x4, sub + 64);
    #undef ACC

    // 16-lane butterfly
    #pragma unroll
    for (int off = 8; off >= 1; off >>= 1) {
        a0 += __shfl_xor(a0, off);
        a1 += __shfl_xor(a1, off);
        a2 += __shfl_xor(a2, off);
        a3 += __shfl_xor(a3, off);
        a4 += __shfl_xor(a4, off);
    }

    if (sub < NP) {
        const float a = (sub == 0) ? a0 : (sub == 1) ? a1 : (sub == 2) ? a2
                       : (sub == 3) ? a3 : a4;
        lds_v[g][sub] = fast_sigmoid(a + b[7 * sub + 1]);
    }
    __syncthreads();

    // Wave 0: the block's 16 window products, reduce, one plain store.
    if (tid < 64) {
        float p = 0.f;
        const int s = t0 + tid;
        if (tid < TB && s <= T_LEN - NP) {
            p = lds_v[tid + 0][0] * lds_v[tid + 1][1] * lds_v[tid + 2][2]
              * lds_v[tid + 3][3] * lds_v[tid + 4][4];
        }
        #pragma unroll
        for (int off = 32; off >= 1; off >>= 1) p += __shfl_xor(p, off);
        if (tid == 0) partial[blockIdx.x] = p;
    }
}

// Single block sums the 2048 per-block partials; plain store to out[0].
__global__ __launch_bounds__(256) void final_sum(
    const float* __restrict__ partial,  // [NBLK]
    float*       __restrict__ out)
{
    const int tid = threadIdx.x;
    float p = 0.f;
    #pragma unroll
    for (int k = 0; k < NBLK / 256; ++k)
        p += partial[tid + 256 * k];

    #pragma unroll
    for (int off = 32; off >= 1; off >>= 1) p += __shfl_xor(p, off);

    __shared__ float ws[4];
    if ((tid & 63) == 0) ws[tid >> 6] = p;
    __syncthreads();
    if (tid == 0) out[0] = ws[0] + ws[1] + ws[2] + ws[3];
}

extern "C" void kernel_launch(void* const* d_in, const int* in_sizes, int n_in,
                              void* d_out, int out_size, void* d_ws, size_t ws_size,
                              hipStream_t stream) {
    const int*   doc = (const int*)  d_in[0];
    const float* emb = (const float*)d_in[1];
    const float* w   = (const float*)d_in[2];
    const float* b   = (const float*)d_in[3];
    float*       out = (float*)d_out;
    float*       partial = (float*)d_ws;   // 2048 * 4 B

    fused_block<<<NBLK, 320, 0, stream>>>(doc, emb, w, b, partial);
    final_sum<<<1, 256, 0, stream>>>(partial, out);
}